// Round 6
// baseline (635.983 us; speedup 1.0000x reference)
//
#include <hip/hip_runtime.h>
#include <hip/hip_bf16.h>
#include <math.h>

#define HID   4096
#define NH    32
#define NG    8
#define DH    128
#define SEQ   2048
#define QKV_N 6144   // 4096 q | 1024 k | 1024 v
#define KOFF  4096
#define VOFF  5120

typedef __bf16 bf16x8 __attribute__((ext_vector_type(8)));
typedef float  f32x4  __attribute__((ext_vector_type(4)));
using bf16 = __hip_bfloat16;

#define LOG2E 1.4426950408889634f
#define SCALE 0.08838834764831845f   // 1/sqrt(128)

// ---- async global->LDS 16B (wave-uniform LDS base + lane*16) ----
typedef const __attribute__((address_space(1))) void* gas_p;
typedef __attribute__((address_space(3))) void* las_p;
__device__ __forceinline__ void async_copy16(void* lds, const void* g) {
  __builtin_amdgcn_global_load_lds((gas_p)g, (las_p)lds, 16, 0, 0);
}

__device__ __forceinline__ unsigned pack2(float a, float b) {
  union { bf16 h[2]; unsigned u; } t;
  t.h[0] = __float2bfloat16(a);
  t.h[1] = __float2bfloat16(b);
  return t.u;
}

// ---------------- elementwise cast X -> bf16 ----------------
__global__ void cast_x_kernel(const float* __restrict__ x, bf16* __restrict__ y, int n4) {
  int i = blockIdx.x * blockDim.x + threadIdx.x;
  if (i >= n4) return;
  float4 v = ((const float4*)x)[i];
  union { bf16 h[4]; uint2 u; } t;
  t.h[0] = __float2bfloat16(v.x);
  t.h[1] = __float2bfloat16(v.y);
  t.h[2] = __float2bfloat16(v.z);
  t.h[3] = __float2bfloat16(v.w);
  ((uint2*)y)[i] = t.u;
}

// ---- unified weight transpose: all 4 matrices in ONE launch (64x64 tiles) ----
__global__ __launch_bounds__(256) void wtrans_all_kernel(const float* __restrict__ Wq, const float* __restrict__ Wk,
                                                         const float* __restrict__ Wv, const float* __restrict__ Wo,
                                                         bf16* __restrict__ Wqkv_t, bf16* __restrict__ Wot) {
  __shared__ bf16 T[64][72];
  const int bx = blockIdx.x;
  const float* W; bf16* dst; int N, ntile;
  if (bx < 64)      { W = Wq; dst = Wqkv_t;                      N = 4096; ntile = bx; }
  else if (bx < 80) { W = Wk; dst = Wqkv_t + (size_t)KOFF * HID; N = 1024; ntile = bx - 64; }
  else if (bx < 96) { W = Wv; dst = Wqkv_t + (size_t)VOFF * HID; N = 1024; ntile = bx - 80; }
  else              { W = Wo; dst = Wot;                         N = 4096; ntile = bx - 96; }
  const int n0 = ntile * 64, k0 = blockIdx.y * 64;
  const int t = threadIdx.x;
  const int nn = (t & 15) * 4, kk = t >> 4;
#pragma unroll
  for (int p = 0; p < 4; ++p) {
    const int k = kk + p * 16;
    float4 v = *(const float4*)&W[(size_t)(k0 + k) * N + n0 + nn];
    union { bf16 h[4]; uint2 u; } c;
    c.h[0] = __float2bfloat16(v.x);
    c.h[1] = __float2bfloat16(v.y);
    c.h[2] = __float2bfloat16(v.z);
    c.h[3] = __float2bfloat16(v.w);
    *(uint2*)&T[k][nn] = c.u;
  }
  __syncthreads();
  const int kc = t & 7, nr = t >> 3;
#pragma unroll
  for (int p = 0; p < 2; ++p) {
    const int n = nr + p * 32;
    union { bf16 h[8]; uint4 u; } o;
#pragma unroll
    for (int i = 0; i < 8; ++i) o.h[i] = T[kc * 8 + i][n];
    *(uint4*)&dst[(size_t)(n0 + n) * HID + k0 + kc * 8] = o.u;
  }
}

__global__ void bias_concat_kernel(const float* __restrict__ bq, const float* __restrict__ bk,
                                   const float* __restrict__ bv, float* __restrict__ dst) {
  int i = blockIdx.x * blockDim.x + threadIdx.x;
  if (i < 4096)       dst[i] = bq[i];
  else if (i < 5120)  dst[i] = bk[i - 4096];
  else if (i < 6144)  dst[i] = bv[i - 5120];
}

// ---------------- GEMM: C[M][N] = A[M][K] @ Bt[N][K]^T + bias ----------------
// Plain 2-D grid (n fastest) — XCD round-robin friendly. Staging pointers are
// strength-reduced (bump by 32 elems/iter) to cut the v_lshl_add_u64 chains.
__device__ __forceinline__ void st_out(float* C, size_t idx, float v) { C[idx] = v; }
__device__ __forceinline__ void st_out(bf16*  C, size_t idx, float v) { C[idx] = __float2bfloat16(v); }

template <typename OutT>
__global__ __launch_bounds__(256) void gemm_bt_kernel(const bf16* __restrict__ A, const bf16* __restrict__ Bt,
                                                      const float* __restrict__ bias, OutT* __restrict__ C,
                                                      int M, int N, int K) {
  __shared__ alignas(16) bf16 As[128][32];
  __shared__ alignas(16) bf16 Bs[128][32];
  const int tid = threadIdx.x;
  const int w = tid >> 6, lane = tid & 63, quad = lane >> 4, l16 = lane & 15;
  const int wr = w >> 1, wc = w & 1;
  const int m0 = blockIdx.y * 128, n0 = blockIdx.x * 128;
  const int srow = lane >> 2;
  const int scol = (lane & 3) * 8;

  // strength-reduced staging pointers (4 copies of 16 rows each)
  const size_t step64 = (size_t)64 * K;
  const bf16* pa0 = A  + (size_t)(m0 + w * 16 + srow) * K + scol;
  const bf16* pa1 = pa0 + step64;
  const bf16* pb0 = Bt + (size_t)(n0 + w * 16 + srow) * K + scol;
  const bf16* pb1 = pb0 + step64;
  bf16* const la0 = &As[w * 16][0];
  bf16* const la1 = &As[w * 16 + 64][0];
  bf16* const lb0 = &Bs[w * 16][0];
  bf16* const lb1 = &Bs[w * 16 + 64][0];

  f32x4 acc[4][4];
  f32x4 zero4 = {0.f, 0.f, 0.f, 0.f};
#pragma unroll
  for (int mt = 0; mt < 4; ++mt)
#pragma unroll
    for (int nt = 0; nt < 4; ++nt) acc[mt][nt] = zero4;

  const int nIter = K >> 5;
  for (int kb = 0; kb < nIter; ++kb) {
    async_copy16(la0, pa0);
    async_copy16(la1, pa1);
    async_copy16(lb0, pb0);
    async_copy16(lb1, pb1);
    pa0 += 32; pa1 += 32; pb0 += 32; pb1 += 32;
    __syncthreads();
    bf16x8 af[4], bfr[4];
#pragma unroll
    for (int i = 0; i < 4; ++i) {
      af[i]  = *(const bf16x8*)&As[wr * 64 + i * 16 + l16][quad * 8];
      bfr[i] = *(const bf16x8*)&Bs[wc * 64 + i * 16 + l16][quad * 8];
    }
#pragma unroll
    for (int mt = 0; mt < 4; ++mt)
#pragma unroll
      for (int nt = 0; nt < 4; ++nt)
        acc[mt][nt] = __builtin_amdgcn_mfma_f32_16x16x32_bf16(af[mt], bfr[nt], acc[mt][nt], 0, 0, 0);
    __syncthreads();
  }

#pragma unroll
  for (int nt = 0; nt < 4; ++nt) {
    const int col = n0 + wc * 64 + nt * 16 + l16;
    const float bv = bias[col];
#pragma unroll
    for (int mt = 0; mt < 4; ++mt) {
#pragma unroll
      for (int r = 0; r < 4; ++r) {
        const int row = m0 + wr * 64 + mt * 16 + quad * 4 + r;
        st_out(C, (size_t)row * N + col, acc[mt][nt][r] + bv);
      }
    }
  }
}

// ---- fused RoPE (q,k) + V transpose, one launch (disjoint QKV regions) ----
__global__ __launch_bounds__(256) void rope_vtrans_kernel(bf16* __restrict__ qkv, bf16* __restrict__ vt) {
  __shared__ bf16 tle[32][33];
  const int bx = blockIdx.x;
  const int tid = threadIdx.x;
  if (bx < 2560) {
    int t = bx * 256 + tid;
    int c  = t & 7;
    int hs = (t >> 3) % 40;
    int s  = t / 320;
    int base = (hs < 32) ? hs * 128 : KOFF + (hs - 32) * 128;
    bf16* p = qkv + (size_t)s * QKV_N + base + c * 8;
    union { bf16x8 v; bf16 h[8]; } a, b, ra, rb;
    a.v = *(bf16x8*)p;
    b.v = *(bf16x8*)(p + 64);
#pragma unroll
    for (int j = 0; j < 8; ++j) {
      int d = c * 8 + j;
      float inv = expf(d * -0.14391156862f);  // ln(10000)/64
      float ang = (float)s * inv;
      float sn, cs;
      sincosf(ang, &sn, &cs);
      float x1 = __bfloat162float(a.h[j]);
      float x2 = __bfloat162float(b.h[j]);
      ra.h[j] = __float2bfloat16(x1 * cs - x2 * sn);
      rb.h[j] = __float2bfloat16(x1 * sn + x2 * cs);
    }
    *(bf16x8*)p        = ra.v;
    *(bf16x8*)(p + 64) = rb.v;
  } else {
    const int b = bx - 2560;
    const int s0 = (b & 63) * 32, d0 = ((b >> 6) & 3) * 32, g = b >> 8;
    const int tx = tid & 31, ty = tid >> 5;
#pragma unroll
    for (int i = 0; i < 4; ++i)
      tle[ty + i * 8][tx] = qkv[(size_t)(s0 + ty + i * 8) * QKV_N + VOFF + g * 128 + d0 + tx];
    __syncthreads();
#pragma unroll
    for (int i = 0; i < 4; ++i)
      vt[(size_t)(g * 128 + d0 + ty + i * 8) * SEQ + s0 + tx] = tle[tx][ty + i * 8];
  }
}

// ---------------- Flash attention v4: wave-private keys ----------------
// Wave w owns keys [w*16, w*16+16) of each KV tile:
//   S^T = K Q^T  : A = 4 ds_read_b128 (own keys), B = Q (all 4 q-subtiles) -> 16 MFMA.
//   P^T B-frag is an IN-LANE identity from S^T's C-layout (C row quad*4+r ==
//   B elem quad*4+j for a K=16 contraction); embedded in the K=32 MFMA with the
//   upper 16 k-slots zeroed on both operands (k-permutation preserves the product).
//   PV: A = V^T via 8 ds_read_b64 -> 32 MFMA (half-empty, MFMA pipe is not the limit).
// LDS reads/wave-iter: 8 KB (was 32 KB); no bpermute chain. O is key-partial
// (128 VGPR) -> cross-wave add + normalize via LDS reduction in the epilogue.
__global__ __launch_bounds__(256, 2) void attn_kernel(const bf16* __restrict__ qkv, const bf16* __restrict__ vt,
                                                      bf16* __restrict__ ctx) {
  __shared__ alignas(16) bf16 Ks[2][64][128];   // 32 KB, overlaid by reduce buf
  __shared__ alignas(16) bf16 Vs[2][128][64];   // 32 KB
  __shared__ float rsbuf[4][16];
  float* const red = (float*)&Ks[0][0][0];      // [w][dt][lane][4] = 32 KB

  const int bx = blockIdx.x;        // 0..15
  const int h  = blockIdx.y;
  const int g  = h >> 2;
  const int tid = threadIdx.x, w = tid >> 6, lane = tid & 63;
  const int quad = lane >> 4, l16 = lane & 15;

  const float c1 = SCALE * LOG2E;
  const float c2 = 12.0f * LOG2E;   // fixed max M0 = 12

  f32x4 zero4 = {0.f, 0.f, 0.f, 0.f};

  auto stage = [&](int kt2, int buf) {
    const bf16* kg = qkv + (size_t)(kt2 * 64) * QKV_N + KOFF + g * 128;
    const bf16* vg = vt + (size_t)(g * 128) * SEQ + kt2 * 64;
#pragma unroll
    for (int i = 0; i < 4; ++i) {
      const int c = (i * 4 + w) * 64 + lane;
      {
        const int key = c >> 4, j = c & 15;
        const int js = (j & 8) | ((j ^ key) & 7);
        async_copy16(&Ks[buf][0][0] + (size_t)(i * 4 + w) * 512,
                     kg + (size_t)key * QKV_N + js * 8);
      }
      {
        const int d = c >> 3, k8 = c & 7;
        const int js = (k8 ^ d) & 7;
        async_copy16(&Vs[buf][0][0] + (size_t)(i * 4 + w) * 512,
                     vg + (size_t)d * SEQ + js * 8);
      }
    }
  };

  for (int ph = 0; ph < 2; ++ph) {
    const int qt = ph ? bx : (31 - bx);
    const int n  = qt + 1;

    // Q fragments for ALL 4 q-subtiles (B-operand): q = t*16 + l16, k = ks*32+quad*8+j
    bf16x8 qf[4][4];
#pragma unroll
    for (int t = 0; t < 4; ++t) {
      const bf16* qp = qkv + (size_t)(qt * 64 + t * 16 + l16) * QKV_N + h * 128 + quad * 8;
#pragma unroll
      for (int ks = 0; ks < 4; ++ks) qf[t][ks] = *(const bf16x8*)(qp + ks * 32);
    }

    f32x4 o[4][8];                 // [q-subtile][dt] partial over this wave's keys
#pragma unroll
    for (int t = 0; t < 4; ++t)
#pragma unroll
      for (int dt = 0; dt < 8; ++dt) o[t][dt] = zero4;
    float rsum[4] = {0.f, 0.f, 0.f, 0.f};

    __syncthreads();               // close previous phase's LDS use (incl. reduce buf)
    stage(0, 0);

    for (int kt = 0; kt < n; ++kt) {
      const int cur = kt & 1;
      __syncthreads();                          // buf 'cur' staged & visible
      if (kt + 1 < n) stage(kt + 1, 1 - cur);   // prefetch behind this iteration

      // ---- S^T rows = own 16 keys; cols = all 64 q ----
      bf16x8 kf[4];
#pragma unroll
      for (int ks = 0; ks < 4; ++ks) {
        const int ch = ks * 4 + quad;
        kf[ks] = *(const bf16x8*)&Ks[cur][w * 16 + l16][((ch & 8) | ((ch ^ l16) & 7)) * 8];
      }
      f32x4 s[4];
#pragma unroll
      for (int t = 0; t < 4; ++t) {
        s[t] = zero4;
#pragma unroll
        for (int ks = 0; ks < 4; ++ks)
          s[t] = __builtin_amdgcn_mfma_f32_16x16x32_bf16(kf[ks], qf[t][ks], s[t], 0, 0, 0);
      }

      // ---- p = exp2(s*c1 - c2) ----
#pragma unroll
      for (int t = 0; t < 4; ++t)
#pragma unroll
        for (int r = 0; r < 4; ++r)
          s[t][r] = exp2f(fmaf(s[t][r], c1, -c2));

      if (kt == qt) {               // diagonal: zero keys > q (tile-local compare)
        const int keyl = w * 16 + quad * 4;
#pragma unroll
        for (int t = 0; t < 4; ++t)
#pragma unroll
          for (int r = 0; r < 4; ++r)
            if (keyl + r > t * 16 + l16) s[t][r] = 0.f;
      }

#pragma unroll
      for (int t = 0; t < 4; ++t)
        rsum[t] += (s[t][0] + s[t][1]) + (s[t][2] + s[t][3]);

      // ---- P^T B-frags: in-lane identity, upper 16 k-slots zero ----
      union { unsigned u[4]; bf16x8 v; } pf[4];
#pragma unroll
      for (int t = 0; t < 4; ++t) {
        pf[t].u[0] = pack2(s[t][0], s[t][1]);
        pf[t].u[1] = pack2(s[t][2], s[t][3]);
        pf[t].u[2] = 0;
        pf[t].u[3] = 0;
      }

      // ---- O^T partial += V^T P^T over own keys ----
      const int vch = ((w * 2 + (quad >> 1)) ^ (l16 & 7)) * 8 + (quad & 1) * 4;
#pragma unroll
      for (int dt = 0; dt < 8; ++dt) {
        union { unsigned u[4]; bf16x8 v; } af;
        *(uint2*)&af.u[0] = *(const uint2*)&Vs[cur][dt * 16 + l16][vch];
        af.u[2] = 0;
        af.u[3] = 0;
#pragma unroll
        for (int t = 0; t < 4; ++t)
          o[t][dt] = __builtin_amdgcn_mfma_f32_16x16x32_bf16(af.v, pf[t].v, o[t][dt], 0, 0, 0);
      }
    }

    // ---- epilogue: cross-wave reduce (4 key-partials), normalize, store ----
    float rst[4];
#pragma unroll
    for (int t = 0; t < 4; ++t) {
      float v = rsum[t];
      v += __shfl_xor(v, 16, 64);
      v += __shfl_xor(v, 32, 64);
      rst[t] = v;                   // uniform across quads, per l16 (=q)
    }
#pragma unroll
    for (int t = 0; t < 4; ++t) {
      __syncthreads();              // round t buffer free (prev round read / K-loop done)
#pragma unroll
      for (int dt = 0; dt < 8; ++dt)
        *(f32x4*)&red[(((w * 8 + dt) * 64) + lane) * 4] = o[t][dt];
      if (quad == 0) rsbuf[w][l16] = rst[t];
      __syncthreads();
#pragma unroll
      for (int i = 0; i < 2; ++i) {
        const int dt = w * 2 + i;
        f32x4 a0 = *(const f32x4*)&red[(((0 * 8 + dt) * 64) + lane) * 4];
        f32x4 a1 = *(const f32x4*)&red[(((1 * 8 + dt) * 64) + lane) * 4];
        f32x4 a2 = *(const f32x4*)&red[(((2 * 8 + dt) * 64) + lane) * 4];
        f32x4 a3 = *(const f32x4*)&red[(((3 * 8 + dt) * 64) + lane) * 4];
        f32x4 sum = (a0 + a1) + (a2 + a3);
        const float inv = 1.0f / (rsbuf[0][l16] + rsbuf[1][l16] + rsbuf[2][l16] + rsbuf[3][l16]);
        union { bf16 hh[4]; uint2 u; } ov;
#pragma unroll
        for (int r = 0; r < 4; ++r) ov.hh[r] = __float2bfloat16(sum[r] * inv);
        *(uint2*)&ctx[(size_t)(qt * 64 + t * 16 + l16) * HID + h * 128 + dt * 16 + quad * 4] = ov.u;
      }
    }
  }
}

// ---------------- launcher ----------------
extern "C" void kernel_launch(void* const* d_in, const int* in_sizes, int n_in,
                              void* d_out, int out_size, void* d_ws, size_t ws_size,
                              hipStream_t stream) {
  const float* X  = (const float*)d_in[0];
  const float* Wq = (const float*)d_in[1];
  const float* bq = (const float*)d_in[2];
  const float* Wk = (const float*)d_in[3];
  const float* bk = (const float*)d_in[4];
  const float* Wv = (const float*)d_in[5];
  const float* bv = (const float*)d_in[6];
  const float* Wo = (const float*)d_in[7];
  const float* bo = (const float*)d_in[8];
  float* out = (float*)d_out;

  char* ws = (char*)d_ws;
  size_t off = 0;
  auto alloc = [&](size_t bytes) { char* p = ws + off; off += (bytes + 255) & ~255ULL; return p; };
  bf16*  Xb     = (bf16*) alloc((size_t)SEQ * HID * 2);
  bf16*  Wqkv_t = (bf16*) alloc((size_t)QKV_N * HID * 2);
  bf16*  Wot    = (bf16*) alloc((size_t)HID * HID * 2);
  float* bqkv   = (float*)alloc((size_t)QKV_N * 4);
  bf16*  QKV    = (bf16*) alloc((size_t)SEQ * QKV_N * 2);
  bf16*  Vt     = (bf16*) alloc((size_t)NG * DH * SEQ * 2);
  bf16*  Ctx    = (bf16*) alloc((size_t)SEQ * HID * 2);

  cast_x_kernel<<<SEQ * HID / 4 / 256, 256, 0, stream>>>(X, Xb, SEQ * HID / 4);
  wtrans_all_kernel<<<dim3(160, HID / 64), 256, 0, stream>>>(Wq, Wk, Wv, Wo, Wqkv_t, Wot);
  bias_concat_kernel<<<QKV_N / 256, 256, 0, stream>>>(bq, bk, bv, bqkv);

  gemm_bt_kernel<bf16><<<dim3(QKV_N / 128, SEQ / 128), 256, 0, stream>>>(Xb, Wqkv_t, bqkv, QKV, SEQ, QKV_N, HID);
  rope_vtrans_kernel<<<2560 + 2048, 256, 0, stream>>>(QKV, Vt);
  attn_kernel<<<dim3(16, NH), 256, 0, stream>>>(QKV, Vt, Ctx);
  gemm_bt_kernel<float><<<dim3(HID / 128, SEQ / 128), 256, 0, stream>>>(Ctx, Wot, bo, out, SEQ, HID, HID);
}

// Round 7
// 538.524 us; speedup vs baseline: 1.1810x; 1.1810x over previous
//
#include <hip/hip_runtime.h>
#include <hip/hip_bf16.h>
#include <math.h>

#define HID   4096
#define NH    32
#define NG    8
#define DH    128
#define SEQ   2048
#define QKV_N 6144   // 4096 q | 1024 k | 1024 v
#define KOFF  4096
#define VOFF  5120

typedef __bf16 bf16x8 __attribute__((ext_vector_type(8)));
typedef float  f32x4  __attribute__((ext_vector_type(4)));
using bf16 = __hip_bfloat16;

#define LOG2E 1.4426950408889634f
#define SCALE 0.08838834764831845f   // 1/sqrt(128)

// ---- async global->LDS 16B (wave-uniform LDS base + lane*16) ----
typedef const __attribute__((address_space(1))) void* gas_p;
typedef __attribute__((address_space(3))) void* las_p;
__device__ __forceinline__ void async_copy16(void* lds, const void* g) {
  __builtin_amdgcn_global_load_lds((gas_p)g, (las_p)lds, 16, 0, 0);
}

__device__ __forceinline__ unsigned pack2(float a, float b) {
  union { bf16 h[2]; unsigned u; } t;
  t.h[0] = __float2bfloat16(a);
  t.h[1] = __float2bfloat16(b);
  return t.u;
}

// ---- unified prepass: weight transposes + X cast + bias concat, ONE launch ----
// bx ranges: [0,64)=Wq, [64,80)=Wk, [80,96)=Wv, [96,160)=Wo (64x64 transpose tiles);
// [160,288) = X cast; bx==288 (by<24) = bias concat.
__global__ __launch_bounds__(256) void prepass_kernel(const float* __restrict__ X,
                                                      const float* __restrict__ Wq, const float* __restrict__ Wk,
                                                      const float* __restrict__ Wv, const float* __restrict__ Wo,
                                                      const float* __restrict__ bq, const float* __restrict__ bk,
                                                      const float* __restrict__ bv,
                                                      bf16* __restrict__ Xb,
                                                      bf16* __restrict__ Wqkv_t, bf16* __restrict__ Wot,
                                                      float* __restrict__ bqkv) {
  const int bx = blockIdx.x, by = blockIdx.y;
  const int t = threadIdx.x;
  if (bx >= 288) {               // bias concat
    if (by < 24) {
      int i = by * 256 + t;
      if (i < 4096)       bqkv[i] = bq[i];
      else if (i < 5120)  bqkv[i] = bk[i - 4096];
      else                bqkv[i] = bv[i - 5120];
    }
    return;
  }
  if (bx >= 160) {               // X cast: float4 per thread
    int i = ((bx - 160) + 128 * by) * 256 + t;
    float4 v = ((const float4*)X)[i];
    union { bf16 h[4]; uint2 u; } c;
    c.h[0] = __float2bfloat16(v.x);
    c.h[1] = __float2bfloat16(v.y);
    c.h[2] = __float2bfloat16(v.z);
    c.h[3] = __float2bfloat16(v.w);
    ((uint2*)Xb)[i] = c.u;
    return;
  }
  __shared__ bf16 T[64][72];
  const float* W; bf16* dst; int N, ntile;
  if (bx < 64)      { W = Wq; dst = Wqkv_t;                      N = 4096; ntile = bx; }
  else if (bx < 80) { W = Wk; dst = Wqkv_t + (size_t)KOFF * HID; N = 1024; ntile = bx - 64; }
  else if (bx < 96) { W = Wv; dst = Wqkv_t + (size_t)VOFF * HID; N = 1024; ntile = bx - 80; }
  else              { W = Wo; dst = Wot;                         N = 4096; ntile = bx - 96; }
  const int n0 = ntile * 64, k0 = by * 64;
  const int nn = (t & 15) * 4, kk = t >> 4;
#pragma unroll
  for (int p = 0; p < 4; ++p) {
    const int k = kk + p * 16;
    float4 v = *(const float4*)&W[(size_t)(k0 + k) * N + n0 + nn];
    union { bf16 h[4]; uint2 u; } c;
    c.h[0] = __float2bfloat16(v.x);
    c.h[1] = __float2bfloat16(v.y);
    c.h[2] = __float2bfloat16(v.z);
    c.h[3] = __float2bfloat16(v.w);
    *(uint2*)&T[k][nn] = c.u;
  }
  __syncthreads();
  const int kc = t & 7, nr = t >> 3;
#pragma unroll
  for (int p = 0; p < 2; ++p) {
    const int n = nr + p * 32;
    union { bf16 h[8]; uint4 u; } o;
#pragma unroll
    for (int i = 0; i < 8; ++i) o.h[i] = T[kc * 8 + i][n];
    *(uint4*)&dst[(size_t)(n0 + n) * HID + k0 + kc * 8] = o.u;
  }
}

// ---------------- GEMM: C[M][N] = A[M][K] @ Bt[N][K]^T + bias ----------------
__device__ __forceinline__ void st_out(float* C, size_t idx, float v) { C[idx] = v; }
__device__ __forceinline__ void st_out(bf16*  C, size_t idx, float v) { C[idx] = __float2bfloat16(v); }

template <typename OutT>
__global__ __launch_bounds__(256) void gemm_bt_kernel(const bf16* __restrict__ A, const bf16* __restrict__ Bt,
                                                      const float* __restrict__ bias, OutT* __restrict__ C,
                                                      int M, int N, int K) {
  __shared__ alignas(16) bf16 As[128][32];
  __shared__ alignas(16) bf16 Bs[128][32];
  const int tid = threadIdx.x;
  const int w = tid >> 6, lane = tid & 63, quad = lane >> 4, l16 = lane & 15;
  const int wr = w >> 1, wc = w & 1;
  const int m0 = blockIdx.y * 128, n0 = blockIdx.x * 128;
  const int srow = lane >> 2;
  const int scol = (lane & 3) * 8;

  const size_t step64 = (size_t)64 * K;
  const bf16* pa0 = A  + (size_t)(m0 + w * 16 + srow) * K + scol;
  const bf16* pa1 = pa0 + step64;
  const bf16* pb0 = Bt + (size_t)(n0 + w * 16 + srow) * K + scol;
  const bf16* pb1 = pb0 + step64;
  bf16* const la0 = &As[w * 16][0];
  bf16* const la1 = &As[w * 16 + 64][0];
  bf16* const lb0 = &Bs[w * 16][0];
  bf16* const lb1 = &Bs[w * 16 + 64][0];

  f32x4 acc[4][4];
  f32x4 zero4 = {0.f, 0.f, 0.f, 0.f};
#pragma unroll
  for (int mt = 0; mt < 4; ++mt)
#pragma unroll
    for (int nt = 0; nt < 4; ++nt) acc[mt][nt] = zero4;

  const int nIter = K >> 5;
  for (int kb = 0; kb < nIter; ++kb) {
    async_copy16(la0, pa0);
    async_copy16(la1, pa1);
    async_copy16(lb0, pb0);
    async_copy16(lb1, pb1);
    pa0 += 32; pa1 += 32; pb0 += 32; pb1 += 32;
    __syncthreads();
    bf16x8 af[4], bfr[4];
#pragma unroll
    for (int i = 0; i < 4; ++i) {
      af[i]  = *(const bf16x8*)&As[wr * 64 + i * 16 + l16][quad * 8];
      bfr[i] = *(const bf16x8*)&Bs[wc * 64 + i * 16 + l16][quad * 8];
    }
#pragma unroll
    for (int mt = 0; mt < 4; ++mt)
#pragma unroll
      for (int nt = 0; nt < 4; ++nt)
        acc[mt][nt] = __builtin_amdgcn_mfma_f32_16x16x32_bf16(af[mt], bfr[nt], acc[mt][nt], 0, 0, 0);
    __syncthreads();
  }

#pragma unroll
  for (int nt = 0; nt < 4; ++nt) {
    const int col = n0 + wc * 64 + nt * 16 + l16;
    const float bv = bias[col];
#pragma unroll
    for (int mt = 0; mt < 4; ++mt) {
#pragma unroll
      for (int r = 0; r < 4; ++r) {
        const int row = m0 + wr * 64 + mt * 16 + quad * 4 + r;
        st_out(C, (size_t)row * N + col, acc[mt][nt][r] + bv);
      }
    }
  }
}

// ---- fused RoPE (q,k) + V transpose, one launch (disjoint QKV regions) ----
__global__ __launch_bounds__(256) void rope_vtrans_kernel(bf16* __restrict__ qkv, bf16* __restrict__ vt) {
  __shared__ bf16 tle[32][33];
  const int bx = blockIdx.x;
  const int tid = threadIdx.x;
  if (bx < 2560) {
    int t = bx * 256 + tid;
    int c  = t & 7;
    int hs = (t >> 3) % 40;
    int s  = t / 320;
    int base = (hs < 32) ? hs * 128 : KOFF + (hs - 32) * 128;
    bf16* p = qkv + (size_t)s * QKV_N + base + c * 8;
    union { bf16x8 v; bf16 h[8]; } a, b, ra, rb;
    a.v = *(bf16x8*)p;
    b.v = *(bf16x8*)(p + 64);
#pragma unroll
    for (int j = 0; j < 8; ++j) {
      int d = c * 8 + j;
      float inv = expf(d * -0.14391156862f);  // ln(10000)/64
      float ang = (float)s * inv;
      float sn, cs;
      sincosf(ang, &sn, &cs);
      float x1 = __bfloat162float(a.h[j]);
      float x2 = __bfloat162float(b.h[j]);
      ra.h[j] = __float2bfloat16(x1 * cs - x2 * sn);
      rb.h[j] = __float2bfloat16(x1 * sn + x2 * cs);
    }
    *(bf16x8*)p        = ra.v;
    *(bf16x8*)(p + 64) = rb.v;
  } else {
    const int b = bx - 2560;
    const int s0 = (b & 63) * 32, d0 = ((b >> 6) & 3) * 32, g = b >> 8;
    const int tx = tid & 31, ty = tid >> 5;
#pragma unroll
    for (int i = 0; i < 4; ++i)
      tle[ty + i * 8][tx] = qkv[(size_t)(s0 + ty + i * 8) * QKV_N + VOFF + g * 128 + d0 + tx];
    __syncthreads();
#pragma unroll
    for (int i = 0; i < 4; ++i)
      vt[(size_t)(g * 128 + d0 + ty + i * 8) * SEQ + s0 + tx] = tle[tx][ty + i * 8];
  }
}

// ---------------- Flash attention v5: in-block split-KV, 8 waves ----------------
// v3 dataflow (S^T = K Q^T, bpermute P^T, O^T = V^T P^T) but 512-thread blocks:
// wave-group gid=w>>2 handles KV tiles {2*kt2+gid} of 32 keys, own 32KB dbuf LDS.
// Fixed-max softmax => groups combine unnormalized O + rowsum in LDS at the end.
// 2 blocks/CU x 8 waves = 4 waves/SIMD (2x v3's TLP). Balanced: qt+1 iters/group.
__global__ __launch_bounds__(512, 4) void attn_kernel(const bf16* __restrict__ qkv, const bf16* __restrict__ vt,
                                                      bf16* __restrict__ ctx) {
  __shared__ alignas(16) bf16 Ks[2][2][32][128];  // [gid][buf][key][d] xor-swizzled; 32 KB
  __shared__ alignas(16) bf16 Vs[2][2][64][64];   // [gid][buf][d>>1][(d&1)*32+key] pair-packed; 32 KB
  __shared__ float rs1[64];
  float* const red = (float*)&Ks[0][0][0][0];     // epilogue overlay: 64q x 128d fp32 = 32 KB

  const int bx = blockIdx.x;        // 0..15
  const int h  = blockIdx.y;
  const int g  = h >> 2;
  const int tid = threadIdx.x;
  const int w = tid >> 6;           // 0..7
  const int gid = w >> 2, wq = w & 3;
  const int lane = tid & 63, quad = lane >> 4, l16 = lane & 15;

  const float c1 = SCALE * LOG2E;
  const float c2 = 12.0f * LOG2E;   // fixed max M0 = 12

  const int addrA = (((quad & 1) << 5) + l16) * 4;  // bpermute src (quad pair base)
  const int addrB = addrA + 64;
  const bool hiq = quad >= 2;

  f32x4 zero4 = {0.f, 0.f, 0.f, 0.f};

  auto stage = [&](int kt2, int buf) {
    const int ktg = 2 * kt2 + gid;
    const bf16* kg = qkv + (size_t)(ktg * 32) * QKV_N + KOFF + g * 128;
    const bf16* vg = vt + (size_t)(g * 128) * SEQ + ktg * 32;
#pragma unroll
    for (int i = 0; i < 2; ++i) {
      const int c = (i * 4 + wq) * 64 + lane;    // chunk 0..511
      {  // K: 32 keys x 16 chunks
        const int key = c >> 4, j = c & 15;
        const int js = (j & 8) | ((j ^ key) & 7);
        async_copy16(&Ks[gid][buf][0][0] + (size_t)(i * 4 + wq) * 512,
                     kg + (size_t)key * QKV_N + js * 8);
      }
      {  // V: 64 rows (d-pairs) x 8 chunks; slot k8s holds global chunk (k8s^row)&3
        const int row = c >> 3, d = row * 2 + ((c >> 2) & 1), k8s = c & 3;
        const int vjs = (k8s ^ row) & 3;
        async_copy16(&Vs[gid][buf][0][0] + (size_t)(i * 4 + wq) * 512,
                     vg + (size_t)d * SEQ + vjs * 8);
      }
    }
  };

  for (int ph = 0; ph < 2; ++ph) {
    const int qt = ph ? bx : (31 - bx);

    // Q fragments (B-operand): q = qt*64 + wq*16 + l16, k = ks*32 + quad*8 + j
    bf16x8 qf[4];
    {
      const bf16* qp = qkv + (size_t)(qt * 64 + wq * 16 + l16) * QKV_N + h * 128 + quad * 8;
#pragma unroll
      for (int ks = 0; ks < 4; ++ks) qf[ks] = *(const bf16x8*)(qp + ks * 32);
    }

    f32x4 o[8];
#pragma unroll
    for (int dt = 0; dt < 8; ++dt) o[dt] = zero4;
    float rsum = 0.f;

    __syncthreads();               // close previous phase's LDS use (incl. red overlay)
    stage(0, 0);

    for (int kt2 = 0; kt2 <= qt; ++kt2) {
      const int cur = kt2 & 1;
      __syncthreads();                              // group's buf 'cur' staged
      if (kt2 + 1 <= qt) stage(kt2 + 1, 1 - cur);   // prefetch behind this iteration

      // ---- S^T = K Q^T : rows = group's 32 keys, cols = wave's 16 q ----
      f32x4 s[2];
#pragma unroll
      for (int nt = 0; nt < 2; ++nt) {
        s[nt] = zero4;
#pragma unroll
        for (int ks = 0; ks < 4; ++ks) {
          const int ch = ks * 4 + quad;
          bf16x8 kf = *(const bf16x8*)&Ks[gid][cur][nt * 16 + l16][((ch & 8) | ((ch ^ l16) & 7)) * 8];
          s[nt] = __builtin_amdgcn_mfma_f32_16x16x32_bf16(kf, qf[ks], s[nt], 0, 0, 0);
        }
      }

      // ---- p = exp2(s*c1 - c2) ----
#pragma unroll
      for (int nt = 0; nt < 2; ++nt)
#pragma unroll
        for (int r = 0; r < 4; ++r)
          s[nt][r] = exp2f(fmaf(s[nt][r], c1, -c2));

      if (kt2 == qt) {               // diagonal tiles: ktg = 2qt+gid -> koff = gid*32
        const int koff = gid * 32;
        const int q_local = wq * 16 + l16;
#pragma unroll
        for (int nt = 0; nt < 2; ++nt)
#pragma unroll
          for (int r = 0; r < 4; ++r)
            if (koff + nt * 16 + quad * 4 + r > q_local) s[nt][r] = 0.f;
      }

      rsum += (s[0][0] + s[0][1]) + (s[0][2] + s[0][3]) +
              (s[1][0] + s[1][1]) + (s[1][2] + s[1][3]);

      // ---- P^T B-frag (K=32) via wave-local bpermute ----
      unsigned pk[2][2];
#pragma unroll
      for (int nt = 0; nt < 2; ++nt) {
        pk[nt][0] = pack2(s[nt][0], s[nt][1]);
        pk[nt][1] = pack2(s[nt][2], s[nt][3]);
      }
      int a0l = __builtin_amdgcn_ds_bpermute(addrA, (int)pk[0][0]);
      int a1l = __builtin_amdgcn_ds_bpermute(addrA, (int)pk[0][1]);
      int b0l = __builtin_amdgcn_ds_bpermute(addrB, (int)pk[0][0]);
      int b1l = __builtin_amdgcn_ds_bpermute(addrB, (int)pk[0][1]);
      int a0h = __builtin_amdgcn_ds_bpermute(addrA, (int)pk[1][0]);
      int a1h = __builtin_amdgcn_ds_bpermute(addrA, (int)pk[1][1]);
      int b0h = __builtin_amdgcn_ds_bpermute(addrB, (int)pk[1][0]);
      int b1h = __builtin_amdgcn_ds_bpermute(addrB, (int)pk[1][1]);
      union { int u[4]; bf16x8 v; } pf;
      pf.u[0] = hiq ? a0h : a0l;
      pf.u[1] = hiq ? a1h : a1l;
      pf.u[2] = hiq ? b0h : b0l;
      pf.u[3] = hiq ? b1h : b1l;

      // ---- O^T += V^T P^T  (A-frag: d = dt*16+l16, keys quad*8..+8) ----
#pragma unroll
      for (int dt = 0; dt < 8; ++dt) {
        const int d = dt * 16 + l16, row = d >> 1;
        const int slot = (quad ^ row) & 3;
        bf16x8 vf = *(const bf16x8*)&Vs[gid][cur][row][(d & 1) * 32 + slot * 8];
        o[dt] = __builtin_amdgcn_mfma_f32_16x16x32_bf16(vf, pf.v, o[dt], 0, 0, 0);
      }
    }

    // ---- epilogue: reduce rsum across quads, combine groups via LDS, store ----
    rsum += __shfl_xor(rsum, 16, 64);
    rsum += __shfl_xor(rsum, 32, 64);

    __syncthreads();               // all K-loop LDS reads done; red overlay safe
    if (gid == 1) {
#pragma unroll
      for (int dt = 0; dt < 8; ++dt)
        *(f32x4*)&red[(((wq * 8 + dt) * 64) + lane) * 4] = o[dt];
      if (quad == 0) rs1[wq * 16 + l16] = rsum;
    }
    __syncthreads();
    if (gid == 0) {
      const float inv = 1.0f / (rsum + rs1[wq * 16 + l16]);
      const int srow = qt * 64 + wq * 16 + l16;
      bf16* cp = ctx + (size_t)srow * HID + h * 128 + quad * 4;
#pragma unroll
      for (int dt = 0; dt < 8; ++dt) {
        f32x4 sum = o[dt] + *(const f32x4*)&red[(((wq * 8 + dt) * 64) + lane) * 4];
        union { bf16 hh[4]; uint2 u; } ov;
#pragma unroll
        for (int r = 0; r < 4; ++r) ov.hh[r] = __float2bfloat16(sum[r] * inv);
        *(uint2*)(cp + dt * 16) = ov.u;
      }
    }
  }
}

// ---------------- launcher ----------------
extern "C" void kernel_launch(void* const* d_in, const int* in_sizes, int n_in,
                              void* d_out, int out_size, void* d_ws, size_t ws_size,
                              hipStream_t stream) {
  const float* X  = (const float*)d_in[0];
  const float* Wq = (const float*)d_in[1];
  const float* bq = (const float*)d_in[2];
  const float* Wk = (const float*)d_in[3];
  const float* bk = (const float*)d_in[4];
  const float* Wv = (const float*)d_in[5];
  const float* bv = (const float*)d_in[6];
  const float* Wo = (const float*)d_in[7];
  const float* bo = (const float*)d_in[8];
  float* out = (float*)d_out;

  char* ws = (char*)d_ws;
  size_t off = 0;
  auto alloc = [&](size_t bytes) { char* p = ws + off; off += (bytes + 255) & ~255ULL; return p; };
  bf16*  Xb     = (bf16*) alloc((size_t)SEQ * HID * 2);
  bf16*  Wqkv_t = (bf16*) alloc((size_t)QKV_N * HID * 2);
  bf16*  Wot    = (bf16*) alloc((size_t)HID * HID * 2);
  float* bqkv   = (float*)alloc((size_t)QKV_N * 4);
  bf16*  QKV    = (bf16*) alloc((size_t)SEQ * QKV_N * 2);
  bf16*  Vt     = (bf16*) alloc((size_t)NG * DH * SEQ * 2);
  bf16*  Ctx    = (bf16*) alloc((size_t)SEQ * HID * 2);

  prepass_kernel<<<dim3(289, 64), 256, 0, stream>>>(X, Wq, Wk, Wv, Wo, bq, bk, bv,
                                                    Xb, Wqkv_t, Wot, bqkv);
  gemm_bt_kernel<bf16><<<dim3(QKV_N / 128, SEQ / 128), 256, 0, stream>>>(Xb, Wqkv_t, bqkv, QKV, SEQ, QKV_N, HID);
  rope_vtrans_kernel<<<2560 + 2048, 256, 0, stream>>>(QKV, Vt);
  attn_kernel<<<dim3(16, NH), 512, 0, stream>>>(QKV, Vt, Ctx);
  gemm_bt_kernel<float><<<dim3(HID / 128, SEQ / 128), 256, 0, stream>>>(Ctx, Wot, bo, out, SEQ, HID, HID);
}